// Round 6
// baseline (278.972 us; speedup 1.0000x reference)
//
#include <hip/hip_runtime.h>
#include <hip/hip_bf16.h>

// BLSTM: B=1024, T=512, V=128, H=128, HH=64, gates=256/dir.
// R22: half-step phase-split software pipeline.
//   Evidence: R17 (2x4-wave) 734 cyc/step, R21 (4x2-wave) 1101, R19 diet
//   = 0 delta -> every config is bound by the serial per-step chain
//   (bar -> ds_read 120 -> MFMA ~100 -> trans ~130 -> write+drain ~80),
//   not issue. Fix: ONE block/CU (256 blocks = 2048 recurrences exactly),
//   8 rows split into sets S0/S1 pipelined HALF A STEP apart with a
//   mid-step barrier:
//     [publish h1(t); pre-read A0] bar1
//     [MFMA S0 || read A1 || X-prefetch(t+2); trans0; write h0(t+1); MFMA S1]
//     bar2 [trans1 -> h1(t+1) ... crosses into next step's head]
//   Each barrier gates only the OTHER set's publish; read+MFMA latency of
//   one set hides under the trans of the other. R18 failed because both
//   sets sat at the SAME phase — the mid-step barrier is the difference.
//   X-prefetch distance 2 (4-reg rotation) keeps the L2 vmcnt wait
//   off-chain (no second block hides it now).
// Carried: pitch-80 hbuf (0 conflicts), dir-reversed x staging + int4
// offset quads, v_cvt_pk_bf16_f32 RNE h.
// Math bit-identical to R17/R19 per set (same MFMA order, z4 C-in,
// post-MFMA x-add, RNE h): absmax oracle must stay EXACTLY 9.766e-4.

#define T_STEPS 512
#define BATCH   1024
#define VOCAB   128
#define HID     128
#define HH      64
#define NG      256
#define XPITCH  520    // 512 steps + 8 zero guard elems at the high end

#define L2E  1.4426950408889634f
#define L2E2 2.8853900817779268f

typedef __attribute__((ext_vector_type(8))) short bf16x8;
typedef __attribute__((ext_vector_type(4))) float f32x4;
typedef unsigned int  u32;
typedef unsigned short u16;

__device__ __forceinline__ float sigmoid_f(float x) {
    return __builtin_amdgcn_rcpf(1.0f + __builtin_amdgcn_exp2f(-x * L2E));
}
__device__ __forceinline__ float tanh_f(float x) {
    return 1.0f - 2.0f * __builtin_amdgcn_rcpf(1.0f + __builtin_amdgcn_exp2f(x * L2E2));
}
__device__ __forceinline__ u16 f2bf_rne(float f) {
    u32 u = __builtin_bit_cast(u32, f);
    u += 0x7FFFu + ((u >> 16) & 1u);
    return (u16)(u >> 16);
}
// barrier with LDS-only drain: global (tab) prefetch loads are NOT drained —
// their vmcnt wait lands at the use point.
__device__ __forceinline__ void barrier_lgkm() {
    asm volatile("s_waitcnt lgkmcnt(0)\n\ts_barrier" ::: "memory");
}

// ---------------- Kernel 1: tab build + W_hh bf16 convert (fused) ----------
// tab3 layout: [d][v][j][4] = dot(emb[v], W_ih_d[g*64+j]) for g=i,f,g,o.
__global__ __launch_bounds__(256) void build_tab_kernel(
    const float* __restrict__ emb,
    const float* __restrict__ W_ih_f,
    const float* __restrict__ W_ih_b,
    const float* __restrict__ W_hh_f,
    const float* __restrict__ W_hh_b,
    float* __restrict__ tab3,
    u16*   __restrict__ whh_bf)
{
    int v = blockIdx.x, d = blockIdx.y, tid = threadIdx.x;
    int j = tid >> 2, g = tid & 3;
    int gr = g * HH + j;                      // W_ih gate row
    const float* W = d ? W_ih_b : W_ih_f;
    const float4* e4 = (const float4*)(emb + v * HID);
    const float4* w4 = (const float4*)(W + gr * HID);
    float acc = 0.0f;
#pragma unroll
    for (int k = 0; k < HID / 4; ++k) {
        float4 e = e4[k]; float4 w = w4[k];
        acc += e.x * w.x + e.y * w.y + e.z * w.z + e.w * w.w;
    }
    tab3[(d * VOCAB + v) * NG + j * 4 + g] = acc;

    // fused W_hh convert: plain row-major [2][256][64]
    if (tid < 128) {
        const float* Whh = d ? W_hh_b : W_hh_f;
        int idx = v * 128 + tid;              // 0..16383 within this dir
        whh_bf[d * NG * HH + idx] = f2bf_rne(Whh[idx]);
    }
}

// ---------------- Kernel 2: MFMA recurrence (phase-split pipeline) --------
// grid (128,2), block 256 (4 waves), 1 block/CU, 8 rows = 2 sets.
__global__ __launch_bounds__(256, 1) void lstm_rec_kernel(
    const int*  __restrict__ x,        // [1024][512]
    const u16*  __restrict__ whh_bf,   // [2][256][64] bf16 bits
    const float* __restrict__ tab3,    // [2][128][64][4] floats
    float* __restrict__ hfin)          // [2][1024][64]
{
    __shared__ __align__(16) u32 xsT[8][XPITCH];       // dir-reversed, 16640 B
    __shared__ __align__(16) u16 hbuf[2][2][4][80];    // [set][pp][row][80]

    const int tid  = threadIdx.x;
    const int lane = tid & 63;
    const int wave = tid >> 6;           // 0..3
    const int quad = lane >> 4;          // 0..3  == my row within the set
    const int m    = lane & 15;          // my j within wave's 16
    const int dir    = blockIdx.y;
    const int b_base = blockIdx.x * 8;

    // stage x pre-scaled to tab3 byte offset (v<<10), dir-REVERSED so the
    // main loop always walks ascending for both directions.
    for (int i = tid; i < 8 * T_STEPS; i += 256) {
        int bl = i >> 9, t = i & (T_STEPS - 1);
        int ts = dir ? (T_STEPS - 1 - t) : t;
        xsT[bl][ts] = ((u32)x[(b_base + bl) * T_STEPS + t]) << 10;
    }
    if (tid < 64)                         // zero guards [512..519] x 8 rows
        xsT[tid >> 3][T_STEPS + (tid & 7)] = 0;
    for (int i = tid; i < (int)(sizeof(hbuf) / 4); i += 256)
        ((u32*)hbuf)[i] = 0;

    // persistent B-fragments, SHARED by both sets (same dir):
    // tile g = gate g, col m -> gate row g*64+wave*16+m
    const u16* WB = whh_bf + dir * NG * HH;
    bf16x8 Bg[4][2];
#pragma unroll
    for (int g = 0; g < 4; ++g)
#pragma unroll
        for (int kc = 0; kc < 2; ++kc)
            Bg[g][kc] = *(const bf16x8*)(WB + (g * HH + wave * 16 + m) * HH
                                            + kc * 32 + quad * 8);

    const char* tabB = (const char*)tab3 + (size_t)dir * VOCAB * NG * 4;
    const u32 joff = (u32)(wave * 16 + m) * 16u;     // j*16 bytes
    const int aoff = (m >> 2) * 80 + quad * 8;       // A-frag read (u16 units)
    const int woff = quad * 80 + wave * 16 + m;      // h write  (u16 units)

    const f32x4 z4 = {0.f, 0.f, 0.f, 0.f};           // loop-invariant C-in
    float cc0 = 0.f, h0 = 0.f;                       // S0 state (rows 0..3)
    float cc1 = 0.f, h1 = 0.f;                       // S1 state (rows 4..7)

    __syncthreads();   // xsT + hbuf init visible

    // x-offset quads per set (xsT rows: S0=quad, S1=4+quad) and
    // distance-2 X rotation: step t uses XS[t&3], loads into XS[(t+2)&3].
    int4 qC0 = *(const int4*)&xsT[quad][0];
    int4 qC1 = *(const int4*)&xsT[4 + quad][0];
    int4 qN0, qN1;
    float4 XS0[4], XS1[4];
    XS0[0] = *(const float4*)(tabB + (u32)qC0.x + joff);
    XS0[1] = *(const float4*)(tabB + (u32)qC0.y + joff);
    XS1[0] = *(const float4*)(tabB + (u32)qC1.x + joff);
    XS1[1] = *(const float4*)(tabB + (u32)qC1.y + joff);

    auto stepf = [&](int par, const float4 Xc0, const float4 Xc1,
                     float4& Xn0, float4& Xn1, u32 e0, u32 e1) {
        // ---- head: publish h_S1(t), pre-read A0 (published last bar2)
        u32 hb1;
        asm("v_cvt_pk_bf16_f32 %0, %1, %2" : "=v"(hb1) : "v"(h1), "v"(h1));
        u16* w1 = &hbuf[1][par][0][0];
        w1[woff] = (u16)hb1;
        const u16* r0 = &hbuf[0][par][0][0];
        bf16x8 A00 = *(const bf16x8*)(r0 + aoff);         // S0 k 0..31
        bf16x8 A01 = *(const bf16x8*)(r0 + aoff + 32);    // S0 k 32..63

        barrier_lgkm();   // bar1: h_S1(t) visible; A0 reads drained

        // ---- S0 MFMA (A0 already in regs -> starts immediately)
        f32x4 aI = __builtin_amdgcn_mfma_f32_16x16x32_bf16(A00, Bg[0][0], z4, 0, 0, 0);
        f32x4 aF = __builtin_amdgcn_mfma_f32_16x16x32_bf16(A00, Bg[1][0], z4, 0, 0, 0);
        f32x4 aG = __builtin_amdgcn_mfma_f32_16x16x32_bf16(A00, Bg[2][0], z4, 0, 0, 0);
        f32x4 aO = __builtin_amdgcn_mfma_f32_16x16x32_bf16(A00, Bg[3][0], z4, 0, 0, 0);
        aI = __builtin_amdgcn_mfma_f32_16x16x32_bf16(A01, Bg[0][1], aI, 0, 0, 0);
        aF = __builtin_amdgcn_mfma_f32_16x16x32_bf16(A01, Bg[1][1], aF, 0, 0, 0);
        aG = __builtin_amdgcn_mfma_f32_16x16x32_bf16(A01, Bg[2][1], aG, 0, 0, 0);
        aO = __builtin_amdgcn_mfma_f32_16x16x32_bf16(A01, Bg[3][1], aO, 0, 0, 0);

        // ---- A1 reads (h_S1(t) just published) + X prefetch for t+2
        const u16* r1 = &hbuf[1][par][0][0];
        bf16x8 A10 = *(const bf16x8*)(r1 + aoff);
        bf16x8 A11 = *(const bf16x8*)(r1 + aoff + 32);
        Xn0 = *(const float4*)(tabB + e0 + joff);
        Xn1 = *(const float4*)(tabB + e1 + joff);

        // ---- S0 gates + trans -> h0(t+1), write to other pp slot
        float gi0 = aI[0] + Xc0.x;
        float gf0 = aF[0] + Xc0.y;
        float gg0 = aG[0] + Xc0.z;
        float go0 = aO[0] + Xc0.w;
        cc0 = sigmoid_f(gf0) * cc0 + sigmoid_f(gi0) * tanh_f(gg0);
        h0  = sigmoid_f(go0) * tanh_f(cc0);
        u32 hb0;
        asm("v_cvt_pk_bf16_f32 %0, %1, %2" : "=v"(hb0) : "v"(h0), "v"(h0));
        u16* w0 = &hbuf[0][par ^ 1][0][0];
        w0[woff] = (u16)hb0;

        // ---- S1 MFMA (overlaps trans0 in the scheduler's hands)
        f32x4 bI = __builtin_amdgcn_mfma_f32_16x16x32_bf16(A10, Bg[0][0], z4, 0, 0, 0);
        f32x4 bF = __builtin_amdgcn_mfma_f32_16x16x32_bf16(A10, Bg[1][0], z4, 0, 0, 0);
        f32x4 bG = __builtin_amdgcn_mfma_f32_16x16x32_bf16(A10, Bg[2][0], z4, 0, 0, 0);
        f32x4 bO = __builtin_amdgcn_mfma_f32_16x16x32_bf16(A10, Bg[3][0], z4, 0, 0, 0);
        bI = __builtin_amdgcn_mfma_f32_16x16x32_bf16(A11, Bg[0][1], bI, 0, 0, 0);
        bF = __builtin_amdgcn_mfma_f32_16x16x32_bf16(A11, Bg[1][1], bF, 0, 0, 0);
        bG = __builtin_amdgcn_mfma_f32_16x16x32_bf16(A11, Bg[2][1], bG, 0, 0, 0);
        bO = __builtin_amdgcn_mfma_f32_16x16x32_bf16(A11, Bg[3][1], bO, 0, 0, 0);

        barrier_lgkm();   // bar2: h_S0(t+1) visible; A1 reads drained

        // ---- tail: S1 gates + trans -> h1(t+1) (crosses into next head)
        float gi1 = bI[0] + Xc1.x;
        float gf1 = bF[0] + Xc1.y;
        float gg1 = bG[0] + Xc1.z;
        float go1 = bO[0] + Xc1.w;
        cc1 = sigmoid_f(gf1) * cc1 + sigmoid_f(gi1) * tanh_f(gg1);
        h1  = sigmoid_f(go1) * tanh_f(cc1);
    };

    for (int kk = 0; kk < T_STEPS / 4; ++kk) {
        qN0 = *(const int4*)&xsT[quad][4 * kk + 4];       // steps 4kk+4..7
        qN1 = *(const int4*)&xsT[4 + quad][4 * kk + 4];
        stepf(0, XS0[0], XS1[0], XS0[2], XS1[2], (u32)qC0.z, (u32)qC1.z);
        stepf(1, XS0[1], XS1[1], XS0[3], XS1[3], (u32)qC0.w, (u32)qC1.w);
        stepf(0, XS0[2], XS1[2], XS0[0], XS1[0], (u32)qN0.x, (u32)qN1.x);
        stepf(1, XS0[3], XS1[3], XS0[1], XS1[1], (u32)qN0.y, (u32)qN1.y);
        qC0 = qN0; qC1 = qN1;
    }

    // lane owns (b_base+quad, j) for S0 and (b_base+4+quad, j) for S1
    {
        int j = wave * 16 + m;
        hfin[(dir * BATCH + b_base + quad) * HH + j]     = h0;
        hfin[(dir * BATCH + b_base + 4 + quad) * HH + j] = h1;
    }
}

// ---------------- Kernel 3: final FC (W_fc in LDS, 8 rows/block) ----------
__global__ __launch_bounds__(256) void fc_kernel(
    const float* __restrict__ hfin,    // [2][1024][64]
    const float* __restrict__ W_fc,    // [128][128]
    const float* __restrict__ b_fc,    // [128]
    float* __restrict__ out)           // [1024][128]
{
    __shared__ float wfc[HID * 129];   // row-padded: bank stride 129
    __shared__ float hid[8][HID];
    const int tid = threadIdx.x;
    const int b0  = blockIdx.x * 8;

    for (int i = tid; i < HID * HID; i += 256) {
        int r = i >> 7, c = i & 127;
        wfc[r * 129 + c] = W_fc[i];
    }
    for (int i = tid; i < 8 * HID; i += 256) {
        int bb = i >> 7, v = i & 127;
        hid[bb][v] = (v < HH) ? hfin[(0 * BATCH + b0 + bb) * HH + v]
                              : hfin[(1 * BATCH + b0 + bb) * HH + (v - HH)];
    }
    __syncthreads();

    const int v  = tid & 127;
    const int bs = (tid >> 7) * 4;     // rows [bs, bs+4)
    const float bias = b_fc[v];
    const float* wrow = wfc + v * 129;
#pragma unroll
    for (int r = 0; r < 4; ++r) {
        const float* h = hid[bs + r];
        float acc = bias;
#pragma unroll
        for (int k = 0; k < HID; k += 4) {
            acc += wrow[k]     * h[k]     + wrow[k + 1] * h[k + 1]
                 + wrow[k + 2] * h[k + 2] + wrow[k + 3] * h[k + 3];
        }
        out[(b0 + bs + r) * HID + v] = acc;
    }
}

extern "C" void kernel_launch(void* const* d_in, const int* in_sizes, int n_in,
                              void* d_out, int out_size, void* d_ws, size_t ws_size,
                              hipStream_t stream) {
    const int*   x      = (const int*)d_in[0];
    // d_in[1] = lengths : unused by the reference
    const float* emb    = (const float*)d_in[2];
    const float* W_ih_f = (const float*)d_in[3];
    const float* W_hh_f = (const float*)d_in[4];
    const float* W_ih_b = (const float*)d_in[5];
    const float* W_hh_b = (const float*)d_in[6];
    const float* W_fc   = (const float*)d_in[7];
    const float* b_fc   = (const float*)d_in[8];
    float* out = (float*)d_out;

    float* tab3   = (float*)d_ws;                         // 65536 f32
    u16*   whh_bf = (u16*)(tab3 + 2 * VOCAB * NG);        // 32768 u16
    float* hfin   = (float*)(whh_bf + 2 * NG * HH);       // 131072 f32

    build_tab_kernel<<<dim3(VOCAB, 2), 256, 0, stream>>>(
        emb, W_ih_f, W_ih_b, W_hh_f, W_hh_b, tab3, whh_bf);
    lstm_rec_kernel<<<dim3(BATCH / 8, 2), 256, 0, stream>>>(x, whh_bf, tab3, hfin);
    fc_kernel<<<dim3(BATCH / 8), 256, 0, stream>>>(hfin, W_fc, b_fc, out);
}

// Round 7
// 213.763 us; speedup vs baseline: 1.3051x; 1.3051x over previous
//
#include <hip/hip_runtime.h>
#include <hip/hip_bf16.h>

// BLSTM: B=1024, T=512, V=128, H=128, HH=64, gates=256/dir.
// R23: consolidation. Rec = the proven R17/R19 structure (MB=4, 512 blocks,
// two independent 4-wave barrier groups per CU, one barrier/step) — six
// structural alternatives (R16 8-wave, R18 in-stream dual, R20 wave-
// autonomous, R21 2-wave quads, R22 phase-split) all measured slower.
// The new win: FC is FUSED into the rec epilogue. Rec already ends with
// every lane holding its (row, j) h in a register: stage 4x64 h into LDS
// (reusing xsT), each thread dots 64 W_fc elems, and both dir-blocks
// atomicAdd partials into a memset-zeroed out (fadd commutative -> bitwise
// deterministic; dir0 adds bias). Deletes fc_kernel, the hfin HBM
// round-trip, and one graph dispatch (~50us of non-rec time was stable
// across rounds).
// Carried: pitch-80 hbuf (0 conflicts), dir-reversed x staging + int4
// offset quads, v_cvt_pk_bf16_f32 RNE h. setprio dropped (0 measured).
// Rec math bit-identical to R17/R19; FC summation order changes (two
// 64-chains + add vs one 128-chain) — f32 reorder ~1e-6 against the
// 9.77e-4 bf16 floor, inside tolerance.

#define T_STEPS 512
#define BATCH   1024
#define VOCAB   128
#define HID     128
#define HH      64
#define NG      256
#define MB      4      // real batch rows per block (quad-duplicated in M)
#define XPITCH  520    // 512 steps + 8 zero guard elems at the high end

#define L2E  1.4426950408889634f
#define L2E2 2.8853900817779268f

typedef __attribute__((ext_vector_type(8))) short bf16x8;
typedef __attribute__((ext_vector_type(4))) float f32x4;
typedef unsigned int  u32;
typedef unsigned short u16;

__device__ __forceinline__ float sigmoid_f(float x) {
    return __builtin_amdgcn_rcpf(1.0f + __builtin_amdgcn_exp2f(-x * L2E));
}
__device__ __forceinline__ float tanh_f(float x) {
    return 1.0f - 2.0f * __builtin_amdgcn_rcpf(1.0f + __builtin_amdgcn_exp2f(x * L2E2));
}
__device__ __forceinline__ u16 f2bf_rne(float f) {
    u32 u = __builtin_bit_cast(u32, f);
    u += 0x7FFFu + ((u >> 16) & 1u);
    return (u16)(u >> 16);
}
// barrier with LDS-only drain: global (tab) prefetch loads are NOT drained —
// their vmcnt wait lands at the use point.
__device__ __forceinline__ void barrier_lgkm() {
    asm volatile("s_waitcnt lgkmcnt(0)\n\ts_barrier" ::: "memory");
}

// ---------------- Kernel 1: tab build + W_hh bf16 convert (fused) ----------
// tab3 layout: [d][v][j][4] = dot(emb[v], W_ih_d[g*64+j]) for g=i,f,g,o.
__global__ __launch_bounds__(256) void build_tab_kernel(
    const float* __restrict__ emb,
    const float* __restrict__ W_ih_f,
    const float* __restrict__ W_ih_b,
    const float* __restrict__ W_hh_f,
    const float* __restrict__ W_hh_b,
    float* __restrict__ tab3,
    u16*   __restrict__ whh_bf)
{
    int v = blockIdx.x, d = blockIdx.y, tid = threadIdx.x;
    int j = tid >> 2, g = tid & 3;
    int gr = g * HH + j;                      // W_ih gate row
    const float* W = d ? W_ih_b : W_ih_f;
    const float4* e4 = (const float4*)(emb + v * HID);
    const float4* w4 = (const float4*)(W + gr * HID);
    float acc = 0.0f;
#pragma unroll
    for (int k = 0; k < HID / 4; ++k) {
        float4 e = e4[k]; float4 w = w4[k];
        acc += e.x * w.x + e.y * w.y + e.z * w.z + e.w * w.w;
    }
    tab3[(d * VOCAB + v) * NG + j * 4 + g] = acc;

    // fused W_hh convert: plain row-major [2][256][64]
    if (tid < 128) {
        const float* Whh = d ? W_hh_b : W_hh_f;
        int idx = v * 128 + tid;              // 0..16383 within this dir
        whh_bf[d * NG * HH + idx] = f2bf_rne(Whh[idx]);
    }
}

// ---------------- Kernel 2: MFMA recurrence + fused FC epilogue -----------
// grid (256,2), block 256 (4 waves), 2 blocks/CU.
__global__ __launch_bounds__(256, 2) void lstm_rec_kernel(
    const int*  __restrict__ x,        // [1024][512]
    const u16*  __restrict__ whh_bf,   // [2][256][64] bf16 bits
    const float* __restrict__ tab3,    // [2][128][64][4] floats
    const float* __restrict__ W_fc,    // [128][128]
    const float* __restrict__ b_fc,    // [128]
    float* __restrict__ out)           // [1024][128], pre-zeroed
{
    __shared__ __align__(16) u32 xsT[MB][XPITCH];    // dir-reversed, 8320 B
    __shared__ __align__(16) u16 hbuf[2][MB][80];    // [pp][row][80], 640 B

    const int tid  = threadIdx.x;
    const int lane = tid & 63;
    const int wave = tid >> 6;           // 0..3
    const int quad = lane >> 4;          // 0..3  == my batch row
    const int m    = lane & 15;          // my j within wave's 16
    const int dir    = blockIdx.y;
    const int b_base = blockIdx.x * MB;

    // stage x pre-scaled to tab3 byte offset (v<<10), dir-REVERSED so the
    // main loop always walks ascending for both directions.
    for (int i = tid; i < MB * T_STEPS; i += 256) {
        int bl = i >> 9, t = i & (T_STEPS - 1);
        int ts = dir ? (T_STEPS - 1 - t) : t;
        xsT[bl][ts] = ((u32)x[(b_base + bl) * T_STEPS + t]) << 10;
    }
    if (tid < MB * 8)                     // zero guards [512..519] x 4 rows
        xsT[tid >> 3][T_STEPS + (tid & 7)] = 0;
    for (int i = tid; i < (int)(sizeof(hbuf) / 4); i += 256)
        ((u32*)hbuf)[i] = 0;

    // persistent B-fragments: tile g = gate g, col m -> gate row g*64+wave*16+m
    const u16* WB = whh_bf + dir * NG * HH;
    bf16x8 Bg[4][2];
#pragma unroll
    for (int g = 0; g < 4; ++g)
#pragma unroll
        for (int kc = 0; kc < 2; ++kc)
            Bg[g][kc] = *(const bf16x8*)(WB + (g * HH + wave * 16 + m) * HH
                                            + kc * 32 + quad * 8);

    const char* tabB = (const char*)tab3 + (size_t)dir * VOCAB * NG * 4;
    const u32 joff = (u32)(wave * 16 + m) * 16u;     // j*16 bytes
    const int aoff = (m >> 2) * 80 + quad * 8;       // A-frag read (u16 units)
    const int woff = quad * 80 + wave * 16 + m;      // h write  (u16 units)

    const f32x4 z4 = {0.f, 0.f, 0.f, 0.f};           // loop-invariant C-in
    float cc = 0.f, hcur = 0.f;

    __syncthreads();   // xsT + hbuf init visible

    // x-offset quad registers: qA covers steps 8k..8k+3, qB 8k+4..8k+7.
    // Reloads land in the register whose elems are already consumed.
    int4 qA = *(const int4*)&xsT[quad][0];
    int4 qB = *(const int4*)&xsT[quad][4];
    float4 X0 = *(const float4*)(tabB + (u32)qA.x + joff);   // step-0 x-term
    float4 X1;

    auto stepf = [&](int p, const float4 Xc, float4& Xn, u32 e) {
        const u16* rh = &hbuf[p][0][0];
        u16* wh = &hbuf[p ^ 1][0][0];
        bf16x8 Ah0 = *(const bf16x8*)(rh + aoff);         // k 0..31
        bf16x8 Ah1 = *(const bf16x8*)(rh + aoff + 32);    // k 32..63

        // issue x-term load for next step (vmcnt wait lands at next use)
        Xn = *(const float4*)(tabB + e + joff);

        // 4 gate chains, K=64 each; acc[0..3] all equal gates[quad][j]
        f32x4 aI = __builtin_amdgcn_mfma_f32_16x16x32_bf16(Ah0, Bg[0][0], z4, 0, 0, 0);
        f32x4 aF = __builtin_amdgcn_mfma_f32_16x16x32_bf16(Ah0, Bg[1][0], z4, 0, 0, 0);
        f32x4 aG = __builtin_amdgcn_mfma_f32_16x16x32_bf16(Ah0, Bg[2][0], z4, 0, 0, 0);
        f32x4 aO = __builtin_amdgcn_mfma_f32_16x16x32_bf16(Ah0, Bg[3][0], z4, 0, 0, 0);
        aI = __builtin_amdgcn_mfma_f32_16x16x32_bf16(Ah1, Bg[0][1], aI, 0, 0, 0);
        aF = __builtin_amdgcn_mfma_f32_16x16x32_bf16(Ah1, Bg[1][1], aF, 0, 0, 0);
        aG = __builtin_amdgcn_mfma_f32_16x16x32_bf16(Ah1, Bg[2][1], aG, 0, 0, 0);
        aO = __builtin_amdgcn_mfma_f32_16x16x32_bf16(Ah1, Bg[3][1], aO, 0, 0, 0);

        float gi = aI[0] + Xc.x;
        float gf = aF[0] + Xc.y;
        float gg = aG[0] + Xc.z;
        float go = aO[0] + Xc.w;

        cc   = sigmoid_f(gf) * cc + sigmoid_f(gi) * tanh_f(gg);
        hcur = sigmoid_f(go) * tanh_f(cc);

        u32 hb;   // RNE f32->bf16, single instruction (== f2bf_rne bits)
        asm("v_cvt_pk_bf16_f32 %0, %1, %2" : "=v"(hb) : "v"(hcur), "v"(hcur));
        wh[woff] = (u16)hb;

        barrier_lgkm();
    };

    for (int kk = 0; kk < T_STEPS / 8; ++kk) {
        stepf(0, X0, X1, (u32)qA.y);
        stepf(1, X1, X0, (u32)qA.z);
        stepf(0, X0, X1, (u32)qA.w);
        qA = *(const int4*)&xsT[quad][8 * kk + 8];    // steps 8kk+8..11
        stepf(1, X1, X0, (u32)qB.x);
        stepf(0, X0, X1, (u32)qB.y);
        stepf(1, X1, X0, (u32)qB.z);
        stepf(0, X0, X1, (u32)qB.w);
        qB = *(const int4*)&xsT[quad][8 * kk + 12];   // steps 8kk+12..15
        stepf(1, X1, X0, (u32)qA.x);
    }

    // ---------------- fused FC epilogue ----------------
    // stage final h (f32) into LDS, reusing xsT storage: hs[row][j]
    float* hs = (float*)&xsT[0][0];                  // 4*64 f32 = 1 KB
    hs[quad * HH + wave * 16 + m] = hcur;
    __syncthreads();

    // thread t: v = t&127, row-pair rp = t>>7 -> rows {2rp, 2rp+1}.
    // partial[b][v] = sum_j hs[r][j] * W_fc[v][dir*64+j] (+ bias if dir==0);
    // both dir-blocks atomicAdd into pre-zeroed out — fadd is commutative,
    // so the two-add result is bitwise deterministic regardless of order.
    {
        const int v  = tid & 127;
        const int rp = tid >> 7;
        const int r0 = 2 * rp, r1 = 2 * rp + 1;
        const float* wv = W_fc + v * HID + dir * HH;
        const float4* w4 = (const float4*)wv;
        const float4* h4a = (const float4*)(hs + r0 * HH);
        const float4* h4b = (const float4*)(hs + r1 * HH);
        float acc0 = 0.f, acc1 = 0.f;
#pragma unroll
        for (int k = 0; k < HH / 4; ++k) {
            float4 w = w4[k];
            float4 a = h4a[k];
            float4 b = h4b[k];
            acc0 += w.x * a.x + w.y * a.y + w.z * a.z + w.w * a.w;
            acc1 += w.x * b.x + w.y * b.y + w.z * b.z + w.w * b.w;
        }
        if (dir == 0) {
            float bias = b_fc[v];
            acc0 += bias;
            acc1 += bias;
        }
        atomicAdd(&out[(b_base + r0) * HID + v], acc0);
        atomicAdd(&out[(b_base + r1) * HID + v], acc1);
    }
}

extern "C" void kernel_launch(void* const* d_in, const int* in_sizes, int n_in,
                              void* d_out, int out_size, void* d_ws, size_t ws_size,
                              hipStream_t stream) {
    const int*   x      = (const int*)d_in[0];
    // d_in[1] = lengths : unused by the reference
    const float* emb    = (const float*)d_in[2];
    const float* W_ih_f = (const float*)d_in[3];
    const float* W_hh_f = (const float*)d_in[4];
    const float* W_ih_b = (const float*)d_in[5];
    const float* W_hh_b = (const float*)d_in[6];
    const float* W_fc   = (const float*)d_in[7];
    const float* b_fc   = (const float*)d_in[8];
    float* out = (float*)d_out;

    float* tab3   = (float*)d_ws;                         // 65536 f32
    u16*   whh_bf = (u16*)(tab3 + 2 * VOCAB * NG);        // 32768 u16

    hipMemsetAsync(out, 0, out_size, stream);             // atomics target
    build_tab_kernel<<<dim3(VOCAB, 2), 256, 0, stream>>>(
        emb, W_ih_f, W_ih_b, W_hh_f, W_hh_b, tab3, whh_bf);
    lstm_rec_kernel<<<dim3(BATCH / MB, 2), 256, 0, stream>>>(
        x, whh_bf, tab3, W_fc, b_fc, out);
}

// Round 8
// 207.068 us; speedup vs baseline: 1.3472x; 1.0323x over previous
//
#include <hip/hip_runtime.h>
#include <hip/hip_bf16.h>

// BLSTM: B=1024, T=512, V=128, H=128, HH=64, gates=256/dir.
// R24: dispatch-count cut. Rec is pipe-saturated at its structural floor:
// MfmaUtil+VALUBusy ≈ 100% for every 2-block/CU config (R17/R19/R23), i.e.
// step = MFMA-pipe (16 MFMA x ~19.4cy = 310) + VALU-pipe (2 waves x
// [40 VALU + 10 trans x 16cy] = 460) = 770 ≈ 740 measured. The kernel is
// transcendental-throughput-bound (10 quarter-rate trans/output = 70% of
// the VALU pipe); reducing trans count breaks bit-exactness (absmax sits
// at exactly 2^-10 — not risked). All alternative geometries trade
// M-duplication against blocks/CU 1:1 and land on the same sum-floor
// (verified by the model retro-predicting R16-R22 within 10%).
// This round: fold out-zeroing into build_tab (bit-exact safe) and delete
// the hipMemsetAsync dispatch -> 2 dispatches total.
// Rec body byte-identical to R23: absmax must stay EXACTLY 9.766e-4.

#define T_STEPS 512
#define BATCH   1024
#define VOCAB   128
#define HID     128
#define HH      64
#define NG      256
#define MB      4      // real batch rows per block (quad-duplicated in M)
#define XPITCH  520    // 512 steps + 8 zero guard elems at the high end

#define L2E  1.4426950408889634f
#define L2E2 2.8853900817779268f

typedef __attribute__((ext_vector_type(8))) short bf16x8;
typedef __attribute__((ext_vector_type(4))) float f32x4;
typedef unsigned int  u32;
typedef unsigned short u16;

__device__ __forceinline__ float sigmoid_f(float x) {
    return __builtin_amdgcn_rcpf(1.0f + __builtin_amdgcn_exp2f(-x * L2E));
}
__device__ __forceinline__ float tanh_f(float x) {
    return 1.0f - 2.0f * __builtin_amdgcn_rcpf(1.0f + __builtin_amdgcn_exp2f(x * L2E2));
}
__device__ __forceinline__ u16 f2bf_rne(float f) {
    u32 u = __builtin_bit_cast(u32, f);
    u += 0x7FFFu + ((u >> 16) & 1u);
    return (u16)(u >> 16);
}
// barrier with LDS-only drain: global (tab) prefetch loads are NOT drained —
// their vmcnt wait lands at the use point.
__device__ __forceinline__ void barrier_lgkm() {
    asm volatile("s_waitcnt lgkmcnt(0)\n\ts_barrier" ::: "memory");
}

// ---------------- Kernel 1: tab build + W_hh convert + out zero (fused) ----
// tab3 layout: [d][v][j][4] = dot(emb[v], W_ih_d[g*64+j]) for g=i,f,g,o.
__global__ __launch_bounds__(256) void build_tab_kernel(
    const float* __restrict__ emb,
    const float* __restrict__ W_ih_f,
    const float* __restrict__ W_ih_b,
    const float* __restrict__ W_hh_f,
    const float* __restrict__ W_hh_b,
    float* __restrict__ tab3,
    u16*   __restrict__ whh_bf,
    float* __restrict__ out)           // [1024][128] — zeroed here
{
    int v = blockIdx.x, d = blockIdx.y, tid = threadIdx.x;

    // zero the atomics target: 65536 threads x 1 float2 = 131072 floats.
    // rec runs after this kernel on the same stream -> ordering guaranteed.
    {
        int gid = (d * VOCAB + v) * 256 + tid;
        ((float2*)out)[gid] = make_float2(0.f, 0.f);
    }

    int j = tid >> 2, g = tid & 3;
    int gr = g * HH + j;                      // W_ih gate row
    const float* W = d ? W_ih_b : W_ih_f;
    const float4* e4 = (const float4*)(emb + v * HID);
    const float4* w4 = (const float4*)(W + gr * HID);
    float acc = 0.0f;
#pragma unroll
    for (int k = 0; k < HID / 4; ++k) {
        float4 e = e4[k]; float4 w = w4[k];
        acc += e.x * w.x + e.y * w.y + e.z * w.z + e.w * w.w;
    }
    tab3[(d * VOCAB + v) * NG + j * 4 + g] = acc;

    // fused W_hh convert: plain row-major [2][256][64]
    if (tid < 128) {
        const float* Whh = d ? W_hh_b : W_hh_f;
        int idx = v * 128 + tid;              // 0..16383 within this dir
        whh_bf[d * NG * HH + idx] = f2bf_rne(Whh[idx]);
    }
}

// ---------------- Kernel 2: MFMA recurrence + fused FC epilogue -----------
// grid (256,2), block 256 (4 waves), 2 blocks/CU.
__global__ __launch_bounds__(256, 2) void lstm_rec_kernel(
    const int*  __restrict__ x,        // [1024][512]
    const u16*  __restrict__ whh_bf,   // [2][256][64] bf16 bits
    const float* __restrict__ tab3,    // [2][128][64][4] floats
    const float* __restrict__ W_fc,    // [128][128]
    const float* __restrict__ b_fc,    // [128]
    float* __restrict__ out)           // [1024][128], pre-zeroed
{
    __shared__ __align__(16) u32 xsT[MB][XPITCH];    // dir-reversed, 8320 B
    __shared__ __align__(16) u16 hbuf[2][MB][80];    // [pp][row][80], 640 B

    const int tid  = threadIdx.x;
    const int lane = tid & 63;
    const int wave = tid >> 6;           // 0..3
    const int quad = lane >> 4;          // 0..3  == my batch row
    const int m    = lane & 15;          // my j within wave's 16
    const int dir    = blockIdx.y;
    const int b_base = blockIdx.x * MB;

    // stage x pre-scaled to tab3 byte offset (v<<10), dir-REVERSED so the
    // main loop always walks ascending for both directions.
    for (int i = tid; i < MB * T_STEPS; i += 256) {
        int bl = i >> 9, t = i & (T_STEPS - 1);
        int ts = dir ? (T_STEPS - 1 - t) : t;
        xsT[bl][ts] = ((u32)x[(b_base + bl) * T_STEPS + t]) << 10;
    }
    if (tid < MB * 8)                     // zero guards [512..519] x 4 rows
        xsT[tid >> 3][T_STEPS + (tid & 7)] = 0;
    for (int i = tid; i < (int)(sizeof(hbuf) / 4); i += 256)
        ((u32*)hbuf)[i] = 0;

    // persistent B-fragments: tile g = gate g, col m -> gate row g*64+wave*16+m
    const u16* WB = whh_bf + dir * NG * HH;
    bf16x8 Bg[4][2];
#pragma unroll
    for (int g = 0; g < 4; ++g)
#pragma unroll
        for (int kc = 0; kc < 2; ++kc)
            Bg[g][kc] = *(const bf16x8*)(WB + (g * HH + wave * 16 + m) * HH
                                            + kc * 32 + quad * 8);

    const char* tabB = (const char*)tab3 + (size_t)dir * VOCAB * NG * 4;
    const u32 joff = (u32)(wave * 16 + m) * 16u;     // j*16 bytes
    const int aoff = (m >> 2) * 80 + quad * 8;       // A-frag read (u16 units)
    const int woff = quad * 80 + wave * 16 + m;      // h write  (u16 units)

    const f32x4 z4 = {0.f, 0.f, 0.f, 0.f};           // loop-invariant C-in
    float cc = 0.f, hcur = 0.f;

    __syncthreads();   // xsT + hbuf init visible

    // x-offset quad registers: qA covers steps 8k..8k+3, qB 8k+4..8k+7.
    // Reloads land in the register whose elems are already consumed.
    int4 qA = *(const int4*)&xsT[quad][0];
    int4 qB = *(const int4*)&xsT[quad][4];
    float4 X0 = *(const float4*)(tabB + (u32)qA.x + joff);   // step-0 x-term
    float4 X1;

    auto stepf = [&](int p, const float4 Xc, float4& Xn, u32 e) {
        const u16* rh = &hbuf[p][0][0];
        u16* wh = &hbuf[p ^ 1][0][0];
        bf16x8 Ah0 = *(const bf16x8*)(rh + aoff);         // k 0..31
        bf16x8 Ah1 = *(const bf16x8*)(rh + aoff + 32);    // k 32..63

        // issue x-term load for next step (vmcnt wait lands at next use)
        Xn = *(const float4*)(tabB + e + joff);

        // 4 gate chains, K=64 each; acc[0..3] all equal gates[quad][j]
        f32x4 aI = __builtin_amdgcn_mfma_f32_16x16x32_bf16(Ah0, Bg[0][0], z4, 0, 0, 0);
        f32x4 aF = __builtin_amdgcn_mfma_f32_16x16x32_bf16(Ah0, Bg[1][0], z4, 0, 0, 0);
        f32x4 aG = __builtin_amdgcn_mfma_f32_16x16x32_bf16(Ah0, Bg[2][0], z4, 0, 0, 0);
        f32x4 aO = __builtin_amdgcn_mfma_f32_16x16x32_bf16(Ah0, Bg[3][0], z4, 0, 0, 0);
        aI = __builtin_amdgcn_mfma_f32_16x16x32_bf16(Ah1, Bg[0][1], aI, 0, 0, 0);
        aF = __builtin_amdgcn_mfma_f32_16x16x32_bf16(Ah1, Bg[1][1], aF, 0, 0, 0);
        aG = __builtin_amdgcn_mfma_f32_16x16x32_bf16(Ah1, Bg[2][1], aG, 0, 0, 0);
        aO = __builtin_amdgcn_mfma_f32_16x16x32_bf16(Ah1, Bg[3][1], aO, 0, 0, 0);

        float gi = aI[0] + Xc.x;
        float gf = aF[0] + Xc.y;
        float gg = aG[0] + Xc.z;
        float go = aO[0] + Xc.w;

        cc   = sigmoid_f(gf) * cc + sigmoid_f(gi) * tanh_f(gg);
        hcur = sigmoid_f(go) * tanh_f(cc);

        u32 hb;   // RNE f32->bf16, single instruction (== f2bf_rne bits)
        asm("v_cvt_pk_bf16_f32 %0, %1, %2" : "=v"(hb) : "v"(hcur), "v"(hcur));
        wh[woff] = (u16)hb;

        barrier_lgkm();
    };

    for (int kk = 0; kk < T_STEPS / 8; ++kk) {
        stepf(0, X0, X1, (u32)qA.y);
        stepf(1, X1, X0, (u32)qA.z);
        stepf(0, X0, X1, (u32)qA.w);
        qA = *(const int4*)&xsT[quad][8 * kk + 8];    // steps 8kk+8..11
        stepf(1, X1, X0, (u32)qB.x);
        stepf(0, X0, X1, (u32)qB.y);
        stepf(1, X1, X0, (u32)qB.z);
        stepf(0, X0, X1, (u32)qB.w);
        qB = *(const int4*)&xsT[quad][8 * kk + 12];   // steps 8kk+12..15
        stepf(1, X1, X0, (u32)qA.x);
    }

    // ---------------- fused FC epilogue ----------------
    // stage final h (f32) into LDS, reusing xsT storage: hs[row][j]
    float* hs = (float*)&xsT[0][0];                  // 4*64 f32 = 1 KB
    hs[quad * HH + wave * 16 + m] = hcur;
    __syncthreads();

    // thread t: v = t&127, row-pair rp = t>>7 -> rows {2rp, 2rp+1}.
    // partial[b][v] = sum_j hs[r][j] * W_fc[v][dir*64+j] (+ bias if dir==0);
    // both dir-blocks atomicAdd into pre-zeroed out — fadd is commutative,
    // so the two-add result is bitwise deterministic regardless of order.
    {
        const int v  = tid & 127;
        const int rp = tid >> 7;
        const int r0 = 2 * rp, r1 = 2 * rp + 1;
        const float* wv = W_fc + v * HID + dir * HH;
        const float4* w4 = (const float4*)wv;
        const float4* h4a = (const float4*)(hs + r0 * HH);
        const float4* h4b = (const float4*)(hs + r1 * HH);
        float acc0 = 0.f, acc1 = 0.f;
#pragma unroll
        for (int k = 0; k < HH / 4; ++k) {
            float4 w = w4[k];
            float4 a = h4a[k];
            float4 b = h4b[k];
            acc0 += w.x * a.x + w.y * a.y + w.z * a.z + w.w * a.w;
            acc1 += w.x * b.x + w.y * b.y + w.z * b.z + w.w * b.w;
        }
        if (dir == 0) {
            float bias = b_fc[v];
            acc0 += bias;
            acc1 += bias;
        }
        atomicAdd(&out[(b_base + r0) * HID + v], acc0);
        atomicAdd(&out[(b_base + r1) * HID + v], acc1);
    }
}

extern "C" void kernel_launch(void* const* d_in, const int* in_sizes, int n_in,
                              void* d_out, int out_size, void* d_ws, size_t ws_size,
                              hipStream_t stream) {
    const int*   x      = (const int*)d_in[0];
    // d_in[1] = lengths : unused by the reference
    const float* emb    = (const float*)d_in[2];
    const float* W_ih_f = (const float*)d_in[3];
    const float* W_hh_f = (const float*)d_in[4];
    const float* W_ih_b = (const float*)d_in[5];
    const float* W_hh_b = (const float*)d_in[6];
    const float* W_fc   = (const float*)d_in[7];
    const float* b_fc   = (const float*)d_in[8];
    float* out = (float*)d_out;

    float* tab3   = (float*)d_ws;                         // 65536 f32
    u16*   whh_bf = (u16*)(tab3 + 2 * VOCAB * NG);        // 32768 u16

    build_tab_kernel<<<dim3(VOCAB, 2), 256, 0, stream>>>(
        emb, W_ih_f, W_ih_b, W_hh_f, W_hh_b, tab3, whh_bf, out);
    lstm_rec_kernel<<<dim3(BATCH / MB, 2), 256, 0, stream>>>(
        x, whh_bf, tab3, W_fc, b_fc, out);
}